// Round 9
// baseline (327.618 us; speedup 1.0000x reference)
//
#include <hip/hip_runtime.h>

// LSTM B=2048,T=512,I=5,H=128 + linear -> [B,1], fp32 in/out.
// Round 21 = r17/r20 (284us dispatch, best; absmax 9.766e-4) + PARITY-
// MIRRORED step bodies to break 2-wave lockstep stall-alignment.
// THEORY: step 1336cy = ~670cy/SIMD issue (366 MFMA + ~300 VALU/trans; 20
// trans/wave at ~8cy dominate) + ~660cy stall. Both waves of a SIMD leave
// the same barrier running IDENTICAL code -> they hit the ds-latency window
// and the serial trans chains IN PHASE; aligned stalls can't fill each
// other. This is why r14 (chain ILP) and r16 (wave count) were null: co-
// fill only works when co-waves are in different step phases.
// CHANGE: even-parity waves run [MI8 i,f][trans i,f][MI8 g,o][tail]; odd-
// parity waves run [MI8 g,o][trans g,o][MI8 i,f][tail]. De-phasing is in
// the code, survives barrier re-sync. parity = (w ^ (w>>2)) & 1 puts
// opposite parities on one SIMD under BOTH wave->SIMD assignment schemes
// (round-robin pairs (w,w+4) and linear pairs (w,w+1)). NO SGBs (r18:
// compiler-free schedule wins on i8). Per-value FP DAG unchanged ->
// absmax EXACTLY 0.0009765625.
// PREDICTED: win -> 265-278us, MfmaUtil ~32-33; null (+-1%) -> scheduler
// already de-phases, serial chain is the floor, ceiling call next round;
// regress >=3% -> i-cache cost, same ceiling call.
// CLOSURE LEDGER: schedule r12-opt (r13/r15/r18 SGB all -3%); chain ILP
// refuted r14; wave-count down r16 (+18%, conflicts halved as predicted ->
// LDS not critical); precision i8 won r17 (-11%); desync blocks r19 dead
// (spill + 512/BT MI8 arithmetic); trans count = algorithmic min (20/wave).
// Structure: 256 blocks x 8 batches, NT=512 (2 waves/SIMD), row-permuted
// direct cell ownership rho(b)=(b>>1)*4+(b&1), dbuf h + 1 barrier/step,
// i8 h-matmul (W*1024, h*127, exact i32), f16 K=16 x/bias MFMA sc-baked,
// folded activation scales, peeled last step, waves_per_eu(2,2).

#define HH 128
#define II 5
#define TT 512
#define BT 8
#define NT 512
#define K8S 144            // hb8 row stride in bytes (2-way-free banks, 16-aligned)
#define HB8 (16 * K8S)     // hb8 buffer stride in bytes
#define KS 136             // zrow stride in f16 (x path)
#define XT (TT * 8 + 8)    // xs per-batch stride in f16

typedef __attribute__((ext_vector_type(4))) _Float16 half4;
typedef __attribute__((ext_vector_type(4))) float f32x4;
typedef __attribute__((ext_vector_type(4))) int int4v;

#define SIG(u) __builtin_amdgcn_rcpf(1.0f + __builtin_amdgcn_exp2f(u))
#define MF16(A, B, C) __builtin_amdgcn_mfma_f32_16x16x16f16((A), (B), (C), 0, 0, 0)
#define MI8(A, B, C)  __builtin_amdgcn_mfma_i32_16x16x64_i8((A), (B), (C), 0, 0, 0)

// Recombine scales: arg = xp + S * (sc_g / (1024*127))
#define INV_IFO (-1.44269504f / 130048.0f)
#define INV_G   ( 2.88539008f / 130048.0f)

// Common tail: cell update + h quant/write. Values already computed.
#define TAIL(PB, LAST) {                                                        \
    cc0 = fv0 * cc0 + iv0 * gv0;                                                \
    float hv0 = ov0 * (1.0f - 2.0f * SIG(2.88539008f * cc0));                   \
    cc1 = fv1 * cc1 + iv1 * gv1;                                                \
    float hv1 = ov1 * (1.0f - 2.0f * SIG(2.88539008f * cc1));                   \
    if (LAST) {                                                                 \
        hsc[bcell][hcol] = hv0; hsc[bcell + 1][hcol] = hv1;                     \
    } else {                                                                    \
        unsigned char* wp = hwr8 + ((PB) ^ 1) * HB8;                            \
        wp[0]    = (unsigned char)(signed char)(int)rintf(hv0 * 127.0f);        \
        wp[K8S]  = (unsigned char)(signed char)(int)rintf(hv1 * 127.0f);        \
    }                                                                           \
    __syncthreads();                                                            \
}

// Even-parity step: i,f MFMAs -> i,f trans -> g,o MFMAs -> g,o trans -> tail.
#define STEPA(PB, LAST) {                                                       \
    const unsigned char* hp = hrd8 + (PB) * HB8;                                \
    int4v alo = *reinterpret_cast<const int4v*>(hp);                            \
    int4v ahi = *reinterpret_cast<const int4v*>(hp + 64);                       \
    f32x4 xp0 = MF16(ax4, wfx[0], zero4);                                       \
    f32x4 xp1 = MF16(ax4, wfx[1], zero4);                                       \
    f32x4 xp2 = MF16(ax4, wfx[2], zero4);                                       \
    f32x4 xp3 = MF16(ax4, wfx[3], zero4);                                       \
    int4v s0 = MI8(alo, wq[0][0], zeroi); int4v s1 = MI8(alo, wq[1][0], zeroi); \
    s0 = MI8(ahi, wq[0][1], s0);          s1 = MI8(ahi, wq[1][1], s1);          \
    float iv0 = SIG(fmaf((float)s0[0], INV_IFO, xp0[0]));                       \
    float iv1 = SIG(fmaf((float)s0[1], INV_IFO, xp0[1]));                       \
    float fv0 = SIG(fmaf((float)s1[0], INV_IFO, xp1[0]));                       \
    float fv1 = SIG(fmaf((float)s1[1], INV_IFO, xp1[1]));                       \
    int4v s2 = MI8(alo, wq[2][0], zeroi); int4v s3 = MI8(alo, wq[3][0], zeroi); \
    s2 = MI8(ahi, wq[2][1], s2);          s3 = MI8(ahi, wq[3][1], s3);          \
    if (!(LAST)) {                                                              \
        xcur += xinc;                                                           \
        ax4 = *reinterpret_cast<const half4*>(xcur);                            \
    }                                                                           \
    float gv0 = 1.0f - 2.0f * SIG(fmaf((float)s2[0], INV_G, xp2[0]));           \
    float ov0 = SIG(fmaf((float)s3[0], INV_IFO, xp3[0]));                       \
    float gv1 = 1.0f - 2.0f * SIG(fmaf((float)s2[1], INV_G, xp2[1]));           \
    float ov1 = SIG(fmaf((float)s3[1], INV_IFO, xp3[1]));                       \
    TAIL(PB, LAST)                                                              \
}

// Odd-parity step: g,o MFMAs -> g,o trans -> i,f MFMAs -> i,f trans -> tail.
// Same per-value DAG; only inter-value issue order differs.
#define STEPB(PB, LAST) {                                                       \
    const unsigned char* hp = hrd8 + (PB) * HB8;                                \
    int4v alo = *reinterpret_cast<const int4v*>(hp);                            \
    int4v ahi = *reinterpret_cast<const int4v*>(hp + 64);                       \
    f32x4 xp2 = MF16(ax4, wfx[2], zero4);                                       \
    f32x4 xp3 = MF16(ax4, wfx[3], zero4);                                       \
    f32x4 xp0 = MF16(ax4, wfx[0], zero4);                                       \
    f32x4 xp1 = MF16(ax4, wfx[1], zero4);                                       \
    int4v s2 = MI8(alo, wq[2][0], zeroi); int4v s3 = MI8(alo, wq[3][0], zeroi); \
    s2 = MI8(ahi, wq[2][1], s2);          s3 = MI8(ahi, wq[3][1], s3);          \
    float gv0 = 1.0f - 2.0f * SIG(fmaf((float)s2[0], INV_G, xp2[0]));           \
    float ov0 = SIG(fmaf((float)s3[0], INV_IFO, xp3[0]));                       \
    float gv1 = 1.0f - 2.0f * SIG(fmaf((float)s2[1], INV_G, xp2[1]));           \
    float ov1 = SIG(fmaf((float)s3[1], INV_IFO, xp3[1]));                       \
    int4v s0 = MI8(alo, wq[0][0], zeroi); int4v s1 = MI8(alo, wq[1][0], zeroi); \
    s0 = MI8(ahi, wq[0][1], s0);          s1 = MI8(ahi, wq[1][1], s1);          \
    if (!(LAST)) {                                                              \
        xcur += xinc;                                                           \
        ax4 = *reinterpret_cast<const half4*>(xcur);                            \
    }                                                                           \
    float iv0 = SIG(fmaf((float)s0[0], INV_IFO, xp0[0]));                       \
    float iv1 = SIG(fmaf((float)s0[1], INV_IFO, xp0[1]));                       \
    float fv0 = SIG(fmaf((float)s1[0], INV_IFO, xp1[0]));                       \
    float fv1 = SIG(fmaf((float)s1[1], INV_IFO, xp1[1]));                       \
    TAIL(PB, LAST)                                                              \
}

__global__ __launch_bounds__(NT)
__attribute__((amdgpu_waves_per_eu(2, 2)))   // 256-VGPR budget: spill guard
void lstm_r21(const float* __restrict__ x,      // [B,T,I]
              const float* __restrict__ W_ih,   // [4H,I]
              const float* __restrict__ W_hh,   // [4H,H]
              const float* __restrict__ b_ih,   // [4H]
              const float* __restrict__ b_hh,   // [4H]
              const float* __restrict__ W_lin,  // [H]
              const float* __restrict__ b_lin,  // [1]
              float* __restrict__ out,          // [B]
              int B)
{
    __shared__ __align__(16) unsigned char hb8[2][16][K8S]; // h as i8; pad rows 0
    __shared__ __align__(16) _Float16 zrow[KS];         // zeros for pad-row x lanes
    __shared__ __align__(16) _Float16 xs[BT * XT];      // 65.7 KB staged x (f16)
    __shared__ float hsc[BT][HH + 4];                   // final fp32 h

    const int tid  = threadIdx.x;
    const int b0   = blockIdx.x * BT;
    const int lane = tid & 63;
    const int w    = tid >> 6;        // 0..7 -> col group
    const int n    = lane & 15;       // A row index / D col
    const int q    = lane >> 4;
    const int hcol = w * 16 + n;      // this wave's gate columns

    // ---- W_hh as i8, B-layout: lane holds W^T[k][col n] for k=q*16+e (lo)  --
    // and k=64+q*16+e (hi), e=0..15, packed 4 bytes/i32. scale 1024.
    int4v wq[4][2];                   // [gate][half]
    half4 wfx[4];                     // x/bias f16 chunk, K=16, sc-baked
    #pragma unroll
    for (int g = 0; g < 4; ++g) {
        const float sc = (g == 2) ? 2.88539008f : -1.44269504f;
        const int j = g * HH + hcol;
        #pragma unroll
        for (int half = 0; half < 2; ++half) {
            const float* p = W_hh + (size_t)j * HH + half * 64 + q * 16;
            #pragma unroll
            for (int r = 0; r < 4; ++r) {
                int wd = 0;
                #pragma unroll
                for (int u = 0; u < 4; ++u) {
                    int b = (int)rintf(p[r * 4 + u] * 1024.0f);   // |W|*1024<=91
                    wd |= (b & 0xff) << (8 * u);
                }
                wq[g][half][r] = wd;
            }
        }
        #pragma unroll
        for (int e = 0; e < 4; ++e) {
            const int k = q * 4 + e;
            float v = 0.0f;
            if (k < II)       v = W_ih[j * II + k];
            else if (k == II) v = b_ih[j] + b_hh[j];
            wfx[g][e] = (_Float16)(v * sc);
        }
    }

    // ---- zero LDS -----------------------------------------------------------
    for (int idx = tid; idx < 2 * 16 * K8S; idx += NT)
        (&hb8[0][0][0])[idx] = 0;
    if (tid < KS) zrow[tid] = (_Float16)0.0f;
    for (int idx = tid; idx < BT * XT; idx += NT)
        xs[idx] = (_Float16)0.0f;
    __syncthreads();

    // ---- stage x (f16) + constant-1.0 bias column in slot 5 -----------------
    {
        const int lb = tid & 63, bb = tid >> 6;     // 64 threads per batch
        if (b0 + bb < B) {
            const float* xb = x + (size_t)(b0 + bb) * TT * II;
            for (int e = lb * 4; e < TT * II; e += 256) {
                float4 v = *reinterpret_cast<const float4*>(xb + e);
                float vv[4] = {v.x, v.y, v.z, v.w};
                #pragma unroll
                for (int u = 0; u < 4; ++u) {
                    const int ee = e + u;
                    xs[bb * XT + (ee / 5) * 8 + (ee % 5)] = (_Float16)vv[u];
                }
            }
        }
        for (int s = tid; s < BT * TT; s += NT)
            xs[(s >> 9) * XT + (s & 511) * 8 + 5] = (_Float16)1.0f;
    }
    __syncthreads();

    // ---- loop-invariant state ----------------------------------------------
    // Row permutation (r10): batch b -> A-row rho(b) = (b>>1)*4 + (b&1);
    // C/D rows q*4+{0,1} = batches {2q, 2q+1} -> direct cell ownership.
    const int bcell = 2 * q;
    float cc0 = 0.f, cc1 = 0.f;
    const f32x4 zero4 = {0.f, 0.f, 0.f, 0.f};
    const int4v zeroi = {0, 0, 0, 0};
    const bool xreal = ((n & 2) == 0);
    const int  bofn  = (n >> 2) * 2 + (n & 1);      // batch carried by A-row n
    // A-frag (i8 K=64): lane (n,q) reads h bytes k=q*16+0..15 (lo), +64 (hi).
    // Pad rows (n in {2,3,6,7,...}) stay zero from init -> rows contribute 0.
    const unsigned char* hrd8 = &hb8[0][n][0] + q * 16;
    unsigned char*       hwr8 = &hb8[0][q * 4][0] + hcol;
    // x A-frag (K=16): lane supplies k=q*4+e; garbage at k>=8 multiplies zero
    // W cols -> harmless (verified r11).
    const _Float16* xcur = xreal ? (&xs[bofn * XT] + q * 4) : (&zrow[0] + q * 4);
    const int       xinc = xreal ? 8 : 0;

    half4 ax4 = *reinterpret_cast<const half4*>(xcur);   // t=0 preload

    // Parity-mirrored main loops. (w ^ (w>>2)) & 1 gives opposite parities on
    // each SIMD for both round-robin (w,w+4) and linear (w,w+1) wave->SIMD
    // assignment. Wave-uniform branch; barrier counts match (1/step) so the
    // divergent-path s_barriers pair correctly on AMD hardware.
    if (((w ^ (w >> 2)) & 1) == 0) {
        #pragma unroll 1
        for (int k = 0; k < (TT - 2) / 2; ++k) {
            STEPA(0, false);
            STEPA(1, false);
        }
        STEPA(0, false);     // t = 510
        STEPA(1, true);      // t = 511, peeled: fp32 hsc write, no prefetch
    } else {
        #pragma unroll 1
        for (int k = 0; k < (TT - 2) / 2; ++k) {
            STEPB(0, false);
            STEPB(1, false);
        }
        STEPB(0, false);     // t = 510
        STEPB(1, true);      // t = 511, peeled: fp32 hsc write, no prefetch
    }

    // ---- epilogue: out[b0+w] = hsc[w,:] . W_lin + b_lin ---------------------
    float p = hsc[w][lane] * W_lin[lane] + hsc[w][lane + 64] * W_lin[lane + 64];
    #pragma unroll
    for (int off = 32; off > 0; off >>= 1) p += __shfl_down(p, off, 64);
    if (lane == 0 && (b0 + w) < B) out[b0 + w] = p + b_lin[0];
}

extern "C" void kernel_launch(void* const* d_in, const int* in_sizes, int n_in,
                              void* d_out, int out_size, void* d_ws, size_t ws_size,
                              hipStream_t stream) {
    const float* x     = (const float*)d_in[0];
    const float* W_ih  = (const float*)d_in[1];
    const float* W_hh  = (const float*)d_in[2];
    const float* b_ih  = (const float*)d_in[3];
    const float* b_hh  = (const float*)d_in[4];
    const float* W_lin = (const float*)d_in[5];
    const float* b_lin = (const float*)d_in[6];
    float* out = (float*)d_out;

    const int B = in_sizes[0] / (TT * II);          // 2048
    const int grid = (B + BT - 1) / BT;             // 256 blocks, 1 per CU
    lstm_r21<<<grid, NT, 0, stream>>>(x, W_ih, W_hh, b_ih, b_hh,
                                      W_lin, b_lin, out, B);
}